// Round 3
// baseline (5638.625 us; speedup 1.0000x reference)
//
#include <hip/hip_runtime.h>
#include <math.h>

// PoseCNN forward, fp32 reference-faithful implementation.
// Workspace: lifetime-packed, ~452 MiB (h1 lives in d_out).

#define BN_RS 0.99999500003749977f  // 1/sqrt(1 + 1e-5)

__device__ __forceinline__ float sigf(float v) { return 1.0f / (1.0f + expf(-v)); }

// ---------------- conv 3x3 SAME, stride 1 ----------------
// EPI 0: out = relu(conv+b)*bn_s + bn_b      EPI 1: out = sigmoid(conv+b+ebias[b,c])
template<int CO_BLK, int EPI>
__global__ __launch_bounds__(256)
void conv3x3_k(const float* __restrict__ in, const float* __restrict__ wgt,
               const float* __restrict__ cbias, const float* __restrict__ bng,
               const float* __restrict__ bnb, const float* __restrict__ ebias,
               float* __restrict__ out, int Cin, int Cout, int H, int W, int co_groups)
{
    extern __shared__ float s_w[];  // [Cin][CO_BLK][9]
    const int b   = blockIdx.z / co_groups;
    const int cg  = blockIdx.z % co_groups;
    const int co0 = cg * CO_BLK;
    const int tid = threadIdx.x;
    const int nw  = Cin * CO_BLK * 9;
    for (int i = tid; i < nw; i += 256) {
        int k  = i % 9;
        int co = (i / 9) % CO_BLK;
        int ci = i / (9 * CO_BLK);
        int c  = co0 + co;
        s_w[i] = (c < Cout) ? wgt[((long)c * Cin + ci) * 9 + k] : 0.0f;
    }
    __syncthreads();
    const int tx = tid & 15, ty = tid >> 4;
    const int x = blockIdx.x * 16 + tx;
    const int y = blockIdx.y * 16 + ty;
    float acc[CO_BLK];
#pragma unroll
    for (int i = 0; i < CO_BLK; ++i) acc[i] = 0.0f;
    const long chs = (long)H * W;
    const float* ip = in + ((long)b * Cin * H + y) * W + x;
    const bool interior = (blockIdx.x > 0) && (blockIdx.x < gridDim.x - 1) &&
                          (blockIdx.y > 0) && (blockIdx.y < gridDim.y - 1);
    if (interior) {
        for (int ci = 0; ci < Cin; ++ci) {
            const float* p = ip + ci * chs;
            float v0 = p[-W - 1], v1 = p[-W], v2 = p[-W + 1];
            float v3 = p[-1],     v4 = p[0], v5 = p[1];
            float v6 = p[W - 1],  v7 = p[W], v8 = p[W + 1];
            const float* wr = s_w + ci * CO_BLK * 9;
#pragma unroll
            for (int co = 0; co < CO_BLK; ++co) {
                const float* ww = wr + co * 9;
                float a = acc[co];
                a = fmaf(v0, ww[0], a); a = fmaf(v1, ww[1], a); a = fmaf(v2, ww[2], a);
                a = fmaf(v3, ww[3], a); a = fmaf(v4, ww[4], a); a = fmaf(v5, ww[5], a);
                a = fmaf(v6, ww[6], a); a = fmaf(v7, ww[7], a); a = fmaf(v8, ww[8], a);
                acc[co] = a;
            }
        }
    } else {
        const bool ym = y > 0, yp = y < H - 1, xm = x > 0, xp = x < W - 1;
        for (int ci = 0; ci < Cin; ++ci) {
            const float* p = ip + ci * chs;
            float v0 = (ym && xm) ? p[-W - 1] : 0.0f;
            float v1 = ym ? p[-W] : 0.0f;
            float v2 = (ym && xp) ? p[-W + 1] : 0.0f;
            float v3 = xm ? p[-1] : 0.0f;
            float v4 = p[0];
            float v5 = xp ? p[1] : 0.0f;
            float v6 = (yp && xm) ? p[W - 1] : 0.0f;
            float v7 = yp ? p[W] : 0.0f;
            float v8 = (yp && xp) ? p[W + 1] : 0.0f;
            const float* wr = s_w + ci * CO_BLK * 9;
#pragma unroll
            for (int co = 0; co < CO_BLK; ++co) {
                const float* ww = wr + co * 9;
                float a = acc[co];
                a = fmaf(v0, ww[0], a); a = fmaf(v1, ww[1], a); a = fmaf(v2, ww[2], a);
                a = fmaf(v3, ww[3], a); a = fmaf(v4, ww[4], a); a = fmaf(v5, ww[5], a);
                a = fmaf(v6, ww[6], a); a = fmaf(v7, ww[7], a); a = fmaf(v8, ww[8], a);
                acc[co] = a;
            }
        }
    }
#pragma unroll
    for (int co = 0; co < CO_BLK; ++co) {
        int c = co0 + co;
        if (c < Cout) {
            float v = acc[co] + cbias[c];
            if (EPI == 0) v = fmaxf(v, 0.0f) * (bng[c] * BN_RS) + bnb[c];
            else          v = sigf(v + ebias[b * Cout + c]);
            out[(((long)b * Cout + c) * H + y) * W + x] = v;
        }
    }
}

// ---------------- maxpool 2x2 stride 2 ----------------
__global__ __launch_bounds__(256)
void maxpool_k(const float* __restrict__ in, float* __restrict__ out, int BC, int Hi, int Wi)
{
    const int Ho = Hi >> 1, Wo = Wi >> 1;
    const long n = (long)BC * Ho * Wo;
    long idx = (long)blockIdx.x * 256 + threadIdx.x;
    if (idx >= n) return;
    int xo = (int)(idx % Wo);
    int yo = (int)((idx / Wo) % Ho);
    long bc = idx / ((long)Wo * Ho);
    const float* p = in + (bc * Hi + 2 * yo) * Wi + 2 * xo;
    out[idx] = fmaxf(fmaxf(p[0], p[1]), fmaxf(p[Wi], p[Wi + 1]));
}

// ---------------- deconv 2x2 (pixel-shuffle style) + ReLU ----------------
template<int CO_BLK>
__global__ __launch_bounds__(256)
void deconv_k(const float* __restrict__ in, const float* __restrict__ wgt,
              const float* __restrict__ bias, float* __restrict__ out,
              int Cin, int Cout, int Hl, int Wl, int co_groups)
{
    extern __shared__ float s_w[];  // [Cin][CO_BLK][4]
    const int b   = blockIdx.z / co_groups;
    const int cg  = blockIdx.z % co_groups;
    const int co0 = cg * CO_BLK;
    const int tid = threadIdx.x;
    const int nw  = Cin * CO_BLK * 4;
    for (int i = tid; i < nw; i += 256) {
        int q  = i & 3;
        int co = (i >> 2) % CO_BLK;
        int ci = i / (4 * CO_BLK);
        s_w[i] = wgt[((long)ci * Cout + co0 + co) * 4 + q];
    }
    __syncthreads();
    const int tx = tid & 15, ty = tid >> 4;
    const int x = blockIdx.x * 16 + tx;
    const int y = blockIdx.y * 16 + ty;
    float acc[CO_BLK][4];
#pragma unroll
    for (int i = 0; i < CO_BLK; ++i)
#pragma unroll
        for (int q = 0; q < 4; ++q) acc[i][q] = 0.0f;
    const long chs = (long)Hl * Wl;
    const float* ip = in + ((long)b * Cin * Hl + y) * Wl + x;
    for (int ci = 0; ci < Cin; ++ci) {
        float v = ip[ci * chs];
        const float* wr = s_w + ci * CO_BLK * 4;
#pragma unroll
        for (int co = 0; co < CO_BLK; ++co) {
#pragma unroll
            for (int q = 0; q < 4; ++q)
                acc[co][q] = fmaf(v, wr[co * 4 + q], acc[co][q]);
        }
    }
    const int Ho = Hl * 2, Wo = Wl * 2;
#pragma unroll
    for (int co = 0; co < CO_BLK; ++co) {
        int c = co0 + co;
        float bb = bias[c];
        float* op = out + (((long)b * Cout + c) * Ho + 2 * y) * Wo + 2 * x;
        op[0]      = fmaxf(acc[co][0] + bb, 0.0f);
        op[1]      = fmaxf(acc[co][1] + bb, 0.0f);
        op[Wo]     = fmaxf(acc[co][2] + bb, 0.0f);
        op[Wo + 1] = fmaxf(acc[co][3] + bb, 0.0f);
    }
}

// ---------------- head: 1x1 conv 64->33 + sigmoid ----------------
__global__ __launch_bounds__(256)
void head_k(const float* __restrict__ fm, const float* __restrict__ w,
            const float* __restrict__ hb, float* __restrict__ hm)
{
    __shared__ float s_w[64 * 33];
    __shared__ float s_b[33];
    const int tid = threadIdx.x;
    for (int i = tid; i < 64 * 33; i += 256) {
        int co = i % 33, ci = i / 33;
        s_w[i] = w[co * 64 + ci];
    }
    if (tid < 33) s_b[tid] = hb[tid];
    __syncthreads();
    long pix = (long)blockIdx.x * 256 + tid;  // over 16*65536
    int b = (int)(pix >> 16);
    int p = (int)(pix & 65535);
    const float* fp = fm + (long)b * 64 * 65536 + p;
    float acc[33];
#pragma unroll
    for (int i = 0; i < 33; ++i) acc[i] = 0.0f;
    for (int ci = 0; ci < 64; ++ci) {
        float v = fp[(long)ci * 65536];
        const float* wr = s_w + ci * 33;
#pragma unroll
        for (int co = 0; co < 33; ++co) acc[co] = fmaf(v, wr[co], acc[co]);
    }
    float* op = hm + (long)b * 33 * 65536 + p;
#pragma unroll
    for (int co = 0; co < 33; ++co) op[(long)co * 65536] = sigf(acc[co] + s_b[co]);
}

// ---------------- soft-argmax over 256x256 per (b,j) ----------------
__global__ __launch_bounds__(256)
void softargmax_k(const float* __restrict__ hm, float* __restrict__ coords)
{
    __shared__ float r0[256], r1[256], r2[256];
    const int bj = blockIdx.x;
    const int tid = threadIdx.x;
    const float* row = hm + (long)bj * 65536;
    float m = -1e30f;
    for (int i = tid; i < 65536; i += 256) m = fmaxf(m, row[i]);
    r0[tid] = m;
    __syncthreads();
    for (int s = 128; s > 0; s >>= 1) {
        if (tid < s) r0[tid] = fmaxf(r0[tid], r0[tid + s]);
        __syncthreads();
    }
    const float mx = r0[0];
    __syncthreads();
    float s = 0.0f, sx = 0.0f, sy = 0.0f;
    for (int i = tid; i < 65536; i += 256) {
        float e = expf((row[i] - mx) * 10.0f);
        s += e;
        sx += e * (float)(i & 255);
        sy += e * (float)(i >> 8);
    }
    r0[tid] = s; r1[tid] = sx; r2[tid] = sy;
    __syncthreads();
    for (int st = 128; st > 0; st >>= 1) {
        if (tid < st) { r0[tid] += r0[tid + st]; r1[tid] += r1[tid + st]; r2[tid] += r2[tid + st]; }
        __syncthreads();
    }
    if (tid == 0) {
        coords[2 * bj]     = r1[0] / r0[0];  // ix = pred_x*(W-1)
        coords[2 * bj + 1] = r2[0] / r0[0];  // iy
    }
}

// ---------------- bilinear sample + proj (64x64) ----------------
__global__ __launch_bounds__(64)
void joint_k(const float* __restrict__ fm, const float* __restrict__ coords,
             const float* __restrict__ pw, const float* __restrict__ pb,
             float* __restrict__ jf)
{
    __shared__ float s_joint[64];
    const int bj = blockIdx.x;
    const int b = bj / 33;
    const int tid = threadIdx.x;  // channel
    float ix = coords[2 * bj], iy = coords[2 * bj + 1];
    float x0f = fminf(fmaxf(floorf(ix), 0.0f), 255.0f);
    float y0f = fminf(fmaxf(floorf(iy), 0.0f), 255.0f);
    float wx = ix - x0f, wy = iy - y0f;
    int x0 = (int)x0f, y0 = (int)y0f;
    int x1 = min(x0 + 1, 255), y1 = min(y0 + 1, 255);
    const float* base = fm + ((long)b * 64 + tid) * 65536;
    float v00 = base[y0 * 256 + x0], v01 = base[y0 * 256 + x1];
    float v10 = base[y1 * 256 + x0], v11 = base[y1 * 256 + x1];
    s_joint[tid] = v00 * (1 - wx) * (1 - wy) + v01 * wx * (1 - wy)
                 + v10 * (1 - wx) * wy + v11 * wx * wy;
    __syncthreads();
    float a = pb[tid];
    for (int k = 0; k < 64; ++k) a = fmaf(s_joint[k], pw[tid * 64 + k], a);
    jf[(long)bj * 64 + tid] = a;
}

// ---------------- graph message + GRU + mean -> refined_bias ----------------
__device__ const int   d_nbr[33][4] = {
    {0,0,0,0},{1,0,0,0},{2,0,0,0},{3,0,0,0},{4,0,0,0},{5,0,0,0},{6,0,0,0},{7,0,0,0},
    {8,0,0,0},{9,0,0,0},{10,0,0,0},
    {11,12,23,13},{12,11,24,14},{13,11,15,0},{14,12,16,0},{15,13,0,0},{16,14,0,0},
    {17,0,0,0},{18,0,0,0},{19,0,0,0},{20,0,0,0},{21,0,0,0},{22,0,0,0},
    {23,11,24,25},{24,12,23,26},{25,23,27,0},{26,24,28,0},{27,25,0,0},{28,26,0,0},
    {29,0,0,0},{30,0,0,0},{31,0,0,0},{32,0,0,0}};
__device__ const int d_cnt[33] = {1,1,1,1,1,1,1,1,1,1,1,4,4,3,3,2,2,1,1,1,1,1,1,4,4,3,3,2,2,1,1,1,1};

__global__ __launch_bounds__(192)
void gru_k(const float* __restrict__ jf, const float* __restrict__ mw, const float* __restrict__ mb,
           const float* __restrict__ wih, const float* __restrict__ whh,
           const float* __restrict__ bih, const float* __restrict__ bhh,
           float* __restrict__ rbias)
{
    __shared__ float s_mjf[64], s_jf[64], s_msg[64], s_gi[192], s_gh[192], s_ref[64];
    const int bj = blockIdx.x;
    const int b = bj / 33, j = bj % 33;
    const int tid = threadIdx.x;
    if (tid < 64) {
        int cnt = d_cnt[j];
        float s = 0.0f;
        for (int n = 0; n < 4; ++n)
            if (n < cnt) s += jf[((long)b * 33 + d_nbr[j][n]) * 64 + tid];
        s_mjf[tid] = s / (float)cnt;
        s_jf[tid] = jf[(long)bj * 64 + tid];
    }
    __syncthreads();
    if (tid < 64) {
        float a = mb[tid];
        for (int k = 0; k < 64; ++k) a = fmaf(mw[tid * 64 + k], s_mjf[k], a);
        s_msg[tid] = a;
    }
    __syncthreads();
    {
        float a = bih[tid], c = bhh[tid];
        for (int k = 0; k < 64; ++k) {
            a = fmaf(wih[tid * 64 + k], s_msg[k], a);
            c = fmaf(whh[tid * 64 + k], s_jf[k], c);
        }
        s_gi[tid] = a; s_gh[tid] = c;
    }
    __syncthreads();
    if (tid < 64) {
        float r = sigf(s_gi[tid] + s_gh[tid]);
        float z = sigf(s_gi[64 + tid] + s_gh[64 + tid]);
        float n = tanhf(s_gi[128 + tid] + r * s_gh[128 + tid]);
        s_ref[tid] = (1.0f - z) * n + z * s_jf[tid];
    }
    __syncthreads();
    if (tid == 0) {
        float s = 0.0f;
        for (int k = 0; k < 64; ++k) s += s_ref[k];
        rbias[bj] = s * (1.0f / 64.0f);
    }
}

// ---------------- vis branch ----------------
__global__ __launch_bounds__(256)
void vispool_k(const float* __restrict__ enc, float* __restrict__ p)
{
    int idx = blockIdx.x * 256 + threadIdx.x;  // < 65536 = 16*256*4*4
    int v = idx & 3, u = (idx >> 2) & 3, c = (idx >> 4) & 255, b = idx >> 12;
    const float* base = enc + (((long)b * 256 + c) * 64 + u * 16) * 64 + v * 16;
    float s = 0.0f;
    for (int a = 0; a < 16; ++a)
#pragma unroll
        for (int d = 0; d < 16; ++d) s += base[a * 64 + d];
    p[idx] = s * (1.0f / 256.0f);
}

__global__ __launch_bounds__(256)
void visfc1_k(const float* __restrict__ p, const float* __restrict__ w1,
              const float* __restrict__ b1, float* __restrict__ v1)
{
    __shared__ float s_p[4096];
    const int b = blockIdx.x, tid = threadIdx.x;
    for (int i = tid; i < 4096; i += 256) s_p[i] = p[b * 4096 + i];
    __syncthreads();
    float a = b1[tid];
    const float* wr = w1 + (long)tid * 4096;
    for (int k = 0; k < 4096; ++k) a = fmaf(wr[k], s_p[k], a);
    v1[b * 256 + tid] = fmaxf(a, 0.0f);
}

__global__ __launch_bounds__(64)
void visfc2_k(const float* __restrict__ v1, const float* __restrict__ w2,
              const float* __restrict__ b2, float* __restrict__ out)
{
    const int b = blockIdx.x, t = threadIdx.x;
    if (t < 33) {
        float a = b2[t];
        for (int k = 0; k < 256; ++k) a = fmaf(w2[t * 256 + k], v1[b * 256 + k], a);
        out[b * 33 + t] = sigf(a);
    }
}

extern "C" void kernel_launch(void* const* d_in, const int* in_sizes, int n_in,
                              void* d_out, int out_size, void* d_ws, size_t ws_size,
                              hipStream_t stream)
{
    const float* x   = (const float*)d_in[0];
    const float* c1w = (const float*)d_in[1];  const float* c1b = (const float*)d_in[2];
    const float* b1g = (const float*)d_in[3];  const float* b1b = (const float*)d_in[4];
    const float* c2w = (const float*)d_in[5];  const float* c2b = (const float*)d_in[6];
    const float* b2g = (const float*)d_in[7];  const float* b2b = (const float*)d_in[8];
    const float* c3w = (const float*)d_in[9];  const float* c3b = (const float*)d_in[10];
    const float* b3g = (const float*)d_in[11]; const float* b3b = (const float*)d_in[12];
    const float* c4w = (const float*)d_in[13]; const float* c4b = (const float*)d_in[14];
    const float* b4g = (const float*)d_in[15]; const float* b4b = (const float*)d_in[16];
    const float* d1w = (const float*)d_in[17]; const float* d1b = (const float*)d_in[18];
    const float* d2w = (const float*)d_in[19]; const float* d2b = (const float*)d_in[20];
    const float* hw  = (const float*)d_in[21]; const float* hb  = (const float*)d_in[22];
    const float* pw  = (const float*)d_in[23]; const float* pb  = (const float*)d_in[24];
    const float* mw  = (const float*)d_in[25]; const float* mb  = (const float*)d_in[26];
    const float* wih = (const float*)d_in[27]; const float* whh = (const float*)d_in[28];
    const float* bih = (const float*)d_in[29]; const float* bhh = (const float*)d_in[30];
    const float* rw  = (const float*)d_in[31]; const float* rb  = (const float*)d_in[32];
    const float* v1w = (const float*)d_in[33]; const float* v1b = (const float*)d_in[34];
    const float* v2w = (const float*)d_in[35]; const float* v2b = (const float*)d_in[36];

    // ---- lifetime-packed workspace (floats) ----
    // A (67,108,864 fl): h2 (steps 2-3) -> h3 @A[0:33,554,432] (4-5)
    //                    -> p2 @A[33,554,432:41,943,040] (5-6) -> feat_map (8-11)
    // B (16,777,216 fl): p1 (3-4) -> enc (6-14)
    // C (34,603,008 fl): f @C[0:33,554,432] (7-8) -> init_hm (9-13)
    // h1 lives in d_out (dead after step 2; d_out rewritten at steps 13/16).
    float* wsf = (float*)d_ws;
    float* A   = wsf;
    float* B   = wsf + 67108864L;
    float* C   = wsf + 83886080L;
    float* S   = wsf + 118489088L;
    float* CO  = S;               // 1056
    float* JF  = S + 2048;        // 33792
    float* RB  = S + 36864;       // 528
    float* P   = S + 38400;       // 65536
    float* V1  = S + 104448;      // 4096

    float* out_hm  = (float*)d_out;                 // (16,33,256,256)
    float* out_vis = out_hm + 34603008L;            // (16,33)
    float* H1      = out_hm;                        // scratch: h1 (16,32,256,256)
    float* H3      = A;                             // h3 (16,128,128,128)
    float* P2      = A + 33554432L;                 // p2 (16,128,64,64)
    float* F       = C;                             // f  (16,128,128,128)

    // 1) conv1 3->32 @256 -> h1 (in d_out)
    conv3x3_k<8, 0><<<dim3(16, 16, 16 * 4), 256, 3 * 8 * 9 * 4, stream>>>(
        x, c1w, c1b, b1g, b1b, nullptr, H1, 3, 32, 256, 256, 4);
    // 2) conv2 32->64 @256 -> h2 (A)
    conv3x3_k<8, 0><<<dim3(16, 16, 16 * 8), 256, 32 * 8 * 9 * 4, stream>>>(
        H1, c2w, c2b, b2g, b2b, nullptr, A, 32, 64, 256, 256, 8);
    // 3) pool -> p1 (B) (16,64,128,128)
    maxpool_k<<<dim3(65536), 256, 0, stream>>>(A, B, 16 * 64, 256, 256);
    // 4) conv3 64->128 @128 -> h3 (A lo)
    conv3x3_k<8, 0><<<dim3(8, 8, 16 * 16), 256, 64 * 8 * 9 * 4, stream>>>(
        B, c3w, c3b, b3g, b3b, nullptr, H3, 64, 128, 128, 128, 16);
    // 5) pool -> p2 (A hi) (16,128,64,64)
    maxpool_k<<<dim3(32768), 256, 0, stream>>>(H3, P2, 16 * 128, 128, 128);
    // 6) conv4 128->256 @64 -> enc (B)
    conv3x3_k<8, 0><<<dim3(4, 4, 16 * 32), 256, 128 * 8 * 9 * 4, stream>>>(
        P2, c4w, c4b, b4g, b4b, nullptr, B, 128, 256, 64, 64, 32);
    // 7) dc1 256->128, 64->128 -> f (C lo)
    deconv_k<8><<<dim3(4, 4, 16 * 16), 256, 256 * 8 * 4 * 4, stream>>>(
        B, d1w, d1b, F, 256, 128, 64, 64, 16);
    // 8) dc2 128->64, 128->256 -> feat_map (A)
    deconv_k<8><<<dim3(8, 8, 16 * 8), 256, 128 * 8 * 4 * 4, stream>>>(
        F, d2w, d2b, A, 128, 64, 128, 128, 8);
    // 9) head 1x1 + sigmoid -> init_hm (C)
    head_k<<<dim3(4096), 256, 0, stream>>>(A, hw, hb, C);
    // 10) soft-argmax
    softargmax_k<<<dim3(528), 256, 0, stream>>>(C, CO);
    // 11) bilinear + proj (reads feat_map A)
    joint_k<<<dim3(528), 64, 0, stream>>>(A, CO, pw, pb, JF);
    // 12) message + GRU -> refined_bias
    gru_k<<<dim3(528), 192, 0, stream>>>(JF, mw, mb, wih, whh, bih, bhh, RB);
    // 13) refine conv 33->33 @256 + bias + sigmoid -> out_hm
    conv3x3_k<8, 1><<<dim3(16, 16, 16 * 5), 256, 33 * 8 * 9 * 4, stream>>>(
        C, rw, rb, nullptr, nullptr, RB, out_hm, 33, 33, 256, 256, 5);
    // 14) vis pool 16x16 mean -> (16,4096)
    vispool_k<<<dim3(256), 256, 0, stream>>>(B, P);
    // 15) fc1 4096->256 + relu
    visfc1_k<<<dim3(16), 256, 0, stream>>>(P, v1w, v1b, V1);
    // 16) fc2 256->33 + sigmoid
    visfc2_k<<<dim3(16), 64, 0, stream>>>(V1, v2w, v2b, out_vis);
}

// Round 6
// 1820.503 us; speedup vs baseline: 3.0973x; 3.0973x over previous
//
#include <hip/hip_runtime.h>
#include <hip/hip_bf16.h>
#include <math.h>

#define BN_RS 0.99999500003749977f  // 1/sqrt(1 + 1e-5)

typedef __attribute__((ext_vector_type(8))) __bf16 bf16x8;
typedef __attribute__((ext_vector_type(4))) float f32x4;

union U16 { uint4 u; bf16x8 v; __hip_bfloat16 h[8]; };

__device__ __forceinline__ float sigf(float v) { return 1.0f / (1.0f + expf(-v)); }

// ================= weight repack =================
// conv OIHW fp32 -> [tap][CoT][Kp] bf16 (zero padded)
__global__ __launch_bounds__(256)
void repack_conv_w_k(const float* __restrict__ w, __hip_bfloat16* __restrict__ wb,
                     int taps, int Co, int Ci, int CoT, int Kp)
{
    int i = blockIdx.x * 256 + threadIdx.x;
    int tot = taps * CoT * Kp;
    if (i >= tot) return;
    int k = i % Kp, n = (i / Kp) % CoT, t = i / (Kp * CoT);
    float v = (n < Co && k < Ci) ? w[((long)n * Ci + k) * taps + t] : 0.0f;
    wb[i] = __float2bfloat16(v);
}
// deconv (Ci,Co,2,2) fp32 -> [q][Co][Ci] bf16
__global__ __launch_bounds__(256)
void repack_deconv_w_k(const float* __restrict__ w, __hip_bfloat16* __restrict__ wb,
                       int Co, int Ci)
{
    int i = blockIdx.x * 256 + threadIdx.x;
    int tot = 4 * Co * Ci;
    if (i >= tot) return;
    int k = i % Ci, n = (i / Ci) % Co, q = i / (Ci * Co);
    wb[i] = __float2bfloat16(w[((long)k * Co + n) * 4 + q]);
}

// ================= conv1 (3->32, scalar fp32, writes bf16 NHWC) =================
__global__ __launch_bounds__(256)
void conv1_k(const float* __restrict__ x, const float* __restrict__ w,
             const float* __restrict__ cb, const float* __restrict__ g,
             const float* __restrict__ bb, __hip_bfloat16* __restrict__ out)
{
    __shared__ float sw[216];  // [ci][co][t]
    const int tid = threadIdx.x;
    const int b = blockIdx.z >> 2, cg = blockIdx.z & 3, co0 = cg * 8;
    for (int i = tid; i < 216; i += 256) {
        int t = i % 9, co = (i / 9) % 8, ci = i / 72;
        sw[i] = w[((co0 + co) * 3 + ci) * 9 + t];
    }
    __syncthreads();
    const int tx = tid & 15, ty = tid >> 4;
    const int y = blockIdx.y * 16 + ty;
    const int xs = blockIdx.x * 64 + tx;
    float acc[4][8];
#pragma unroll
    for (int p = 0; p < 4; ++p)
#pragma unroll
        for (int c = 0; c < 8; ++c) acc[p][c] = 0.0f;
    for (int ci = 0; ci < 3; ++ci) {
        const float* plane = x + ((long)b * 3 + ci) * 65536;
#pragma unroll
        for (int t = 0; t < 9; ++t) {
            const int dy = t / 3 - 1, dx = t % 3 - 1;
            const int yy = y + dy;
            if ((unsigned)yy < 256u) {
                const float* row = plane + yy * 256;
                float ws[8];
#pragma unroll
                for (int c = 0; c < 8; ++c) ws[c] = sw[ci * 72 + c * 9 + t];
#pragma unroll
                for (int p = 0; p < 4; ++p) {
                    const int xx = xs + p * 16 + dx;
                    const float v = ((unsigned)xx < 256u) ? row[xx] : 0.0f;
#pragma unroll
                    for (int c = 0; c < 8; ++c) acc[p][c] = fmaf(v, ws[c], acc[p][c]);
                }
            }
        }
    }
#pragma unroll
    for (int p = 0; p < 4; ++p) {
        U16 o;
#pragma unroll
        for (int c = 0; c < 8; ++c) {
            const int cc = co0 + c;
            float v = fmaxf(acc[p][c] + cb[cc], 0.0f) * (g[cc] * BN_RS) + bb[cc];
            o.h[c] = __float2bfloat16(v);
        }
        *(uint4*)(void*)(out + (((long)b * 65536 + (long)y * 256 + xs + p * 16) * 32 + co0)) = o.u;
    }
}

// ================= MFMA conv =================
// Wave tile: 64 px (along x) x 64 cout. A: activations NHWC bf16; B: wb[t][CoT][Cin].
// MODE 0: 3x3 + relu/BN -> bf16 NHWC
// MODE 1: 1x1 head + sigmoid -> f32 NCHW (c<33, via LDS transpose) + bf16 NHWC (pad->0)
// MODE 2: 3x3 refine + cbias + ebias + sigmoid -> f32 NCHW (c<33, via LDS transpose)
template<int MODE>
__global__ __launch_bounds__(256)
void mfma_conv_k(const __hip_bfloat16* __restrict__ in,
                 const __hip_bfloat16* __restrict__ wb,
                 const float* __restrict__ cbias,
                 const float* __restrict__ bng, const float* __restrict__ bnb,
                 const float* __restrict__ ebias,
                 __hip_bfloat16* __restrict__ out_bf, float* __restrict__ out_f32,
                 int H, int W, int Cin, int CoutT, int CG, int S)
{
    extern __shared__ float ltr[];  // MODE 1/2: 4 waves x 64ch x 65px f32
    const int tid = threadIdx.x;
    const int wid = tid >> 6, lane = tid & 63;
    const int ln = lane & 15, kg = lane >> 4;
    const int u = blockIdx.x * 4 + wid;
    const int y = u / S, x0 = (u % S) * 64;
    const int b = blockIdx.z / CG, cg = blockIdx.z % CG;
    const int co0 = cg * 64;
    const int KC = Cin >> 5;
    const long inb = (long)b * H * W * Cin;

    f32x4 acc[4][4];
#pragma unroll
    for (int i = 0; i < 4; ++i)
#pragma unroll
        for (int j = 0; j < 4; ++j) acc[i][j] = f32x4{0.f, 0.f, 0.f, 0.f};

    constexpr int NT = (MODE == 1) ? 1 : 9;
    for (int kc = 0; kc < KC; ++kc) {
        const int kofs = kc * 32 + kg * 8;
#pragma unroll
        for (int t = 0; t < NT; ++t) {
            const int dy = (MODE == 1) ? 0 : (t / 3 - 1);
            const int dx = (MODE == 1) ? 0 : (t % 3 - 1);
            bf16x8 bfr[4];
#pragma unroll
            for (int ni = 0; ni < 4; ++ni)
                bfr[ni] = *(const bf16x8*)(const void*)(wb + ((long)t * CoutT + co0 + ni * 16 + ln) * Cin + kofs);
            const int yy = y + dy;
            const bool rok = (unsigned)yy < (unsigned)H;
            const long rowb = inb + (long)yy * W * Cin;
#pragma unroll
            for (int mi = 0; mi < 4; ++mi) {
                const int xx = x0 + mi * 16 + ln + dx;
                U16 av;
                av.u = make_uint4(0u, 0u, 0u, 0u);
                if (rok && (unsigned)xx < (unsigned)W)
                    av.u = *(const uint4*)(const void*)(in + rowb + (long)xx * Cin + kofs);
#pragma unroll
                for (int ni = 0; ni < 4; ++ni)
                    acc[mi][ni] = __builtin_amdgcn_mfma_f32_16x16x32_bf16(av.v, bfr[ni], acc[mi][ni], 0, 0, 0);
            }
        }
    }

    if constexpr (MODE == 0) {
        const long ob = (long)b * H * W * CoutT;
#pragma unroll
        for (int mi = 0; mi < 4; ++mi) {
#pragma unroll
            for (int r = 0; r < 4; ++r) {
                const int px = x0 + mi * 16 + kg * 4 + r;
                const long pb = ob + ((long)y * W + px) * CoutT + co0;
#pragma unroll
                for (int ni = 0; ni < 4; ++ni) {
                    const int c = co0 + ni * 16 + ln;
                    float v = acc[mi][ni][r] + cbias[c];
                    v = fmaxf(v, 0.0f) * (bng[c] * BN_RS) + bnb[c];
                    out_bf[pb + ni * 16 + ln] = __float2bfloat16(v);
                }
            }
        }
    } else {
        float* wt = ltr + wid * 4160;  // 64 x 65
#pragma unroll
        for (int mi = 0; mi < 4; ++mi) {
#pragma unroll
            for (int r = 0; r < 4; ++r) {
                const int pxl = mi * 16 + kg * 4 + r;
                const int px = x0 + pxl;
#pragma unroll
                for (int ni = 0; ni < 4; ++ni) {
                    const int c = co0 + ni * 16 + ln;
                    float v = acc[mi][ni][r];
                    if constexpr (MODE == 1) {
                        v = sigf(v + ((c < 33) ? cbias[c] : 0.0f));
                        out_bf[(long)b * H * W * CoutT + ((long)y * W + px) * CoutT + c] =
                            (c < 33) ? __float2bfloat16(v) : __float2bfloat16(0.0f);
                    } else {
                        float eb = (c < 33) ? (cbias[c] + ebias[b * 33 + c]) : 0.0f;
                        v = sigf(v + eb);
                    }
                    wt[c * 65 + pxl] = v;
                }
            }
        }
        __syncthreads();
        const long o32 = ((long)b * 33) * H * W + (long)y * W + x0 + lane;
        for (int c = 0; c < 33; ++c)
            out_f32[o32 + (long)c * H * W] = wt[c * 65 + lane];
    }
}

// ================= MFMA deconv 2x2 + ReLU (bf16 NHWC out, 2x upsample) =================
__global__ __launch_bounds__(256)
void mfma_deconv_k(const __hip_bfloat16* __restrict__ in,
                   const __hip_bfloat16* __restrict__ wb,
                   const float* __restrict__ bias,
                   __hip_bfloat16* __restrict__ out,
                   int H, int W, int Cin, int CoutT, int CG, int S)
{
    const int tid = threadIdx.x;
    const int wid = tid >> 6, lane = tid & 63;
    const int ln = lane & 15, kg = lane >> 4;
    const int u = blockIdx.x * 4 + wid;
    const int y = u / S, x0 = (u % S) * 64;
    const int b = blockIdx.z / CG, cg = blockIdx.z % CG;
    const int co0 = cg * 64;
    const int KC = Cin >> 5;
    const long inb = (long)b * H * W * Cin;
    const int W2 = W * 2;
    const long ob = (long)b * 4 * H * W * CoutT;

    for (int q = 0; q < 4; ++q) {
        const int dy = q >> 1, dx = q & 1;
        f32x4 acc[4][4];
#pragma unroll
        for (int i = 0; i < 4; ++i)
#pragma unroll
            for (int j = 0; j < 4; ++j) acc[i][j] = f32x4{0.f, 0.f, 0.f, 0.f};
        for (int kc = 0; kc < KC; ++kc) {
            const int kofs = kc * 32 + kg * 8;
            bf16x8 bfr[4];
#pragma unroll
            for (int ni = 0; ni < 4; ++ni)
                bfr[ni] = *(const bf16x8*)(const void*)(wb + ((long)q * CoutT + co0 + ni * 16 + ln) * Cin + kofs);
#pragma unroll
            for (int mi = 0; mi < 4; ++mi) {
                const int xx = x0 + mi * 16 + ln;
                U16 av;
                av.u = *(const uint4*)(const void*)(in + inb + ((long)y * W + xx) * Cin + kofs);
#pragma unroll
                for (int ni = 0; ni < 4; ++ni)
                    acc[mi][ni] = __builtin_amdgcn_mfma_f32_16x16x32_bf16(av.v, bfr[ni], acc[mi][ni], 0, 0, 0);
            }
        }
#pragma unroll
        for (int mi = 0; mi < 4; ++mi) {
#pragma unroll
            for (int r = 0; r < 4; ++r) {
                const int xl = x0 + mi * 16 + kg * 4 + r;
                const long pb = ob + ((long)(2 * y + dy) * W2 + 2 * xl + dx) * CoutT + co0;
#pragma unroll
                for (int ni = 0; ni < 4; ++ni) {
                    const int c = co0 + ni * 16 + ln;
                    float v = fmaxf(acc[mi][ni][r] + bias[c], 0.0f);
                    out[pb + ni * 16 + ln] = __float2bfloat16(v);
                }
            }
        }
    }
}

// ================= maxpool 2x2 on bf16 NHWC =================
__global__ __launch_bounds__(256)
void maxpool_bf_k(const __hip_bfloat16* __restrict__ in, __hip_bfloat16* __restrict__ out,
                  int Ho, int Wo, int C, long total)
{
    long idx = (long)blockIdx.x * 256 + threadIdx.x;
    if (idx >= total) return;
    const int ng = C >> 3;
    const int cg = (int)(idx % ng);
    long pix = idx / ng;
    const int xo = (int)(pix % Wo); pix /= Wo;
    const int yo = (int)(pix % Ho);
    const int b = (int)(pix / Ho);
    const int Wi = Wo * 2;
    const __hip_bfloat16* p = in + (((long)b * 2 * Ho + 2 * yo) * Wi + 2 * xo) * C + cg * 8;
    U16 a0, a1, a2, a3, o;
    a0.u = *(const uint4*)(const void*)p;
    a1.u = *(const uint4*)(const void*)(p + C);
    a2.u = *(const uint4*)(const void*)(p + (long)Wi * C);
    a3.u = *(const uint4*)(const void*)(p + (long)Wi * C + C);
#pragma unroll
    for (int j = 0; j < 8; ++j) {
        float m = fmaxf(fmaxf(__bfloat162float(a0.h[j]), __bfloat162float(a1.h[j])),
                        fmaxf(__bfloat162float(a2.h[j]), __bfloat162float(a3.h[j])));
        o.h[j] = __float2bfloat16(m);
    }
    *(uint4*)(void*)(out + (((long)b * Ho + yo) * Wo + xo) * C + cg * 8) = o.u;
}

// ================= soft-argmax (f32 NCHW heatmap) =================
__global__ __launch_bounds__(256)
void softargmax_k(const float* __restrict__ hm, float* __restrict__ coords)
{
    __shared__ float r0[256], r1[256], r2[256];
    const int bj = blockIdx.x;
    const int tid = threadIdx.x;
    const float* row = hm + (long)bj * 65536;
    float m = -1e30f;
    for (int i = tid; i < 65536; i += 256) m = fmaxf(m, row[i]);
    r0[tid] = m;
    __syncthreads();
    for (int s = 128; s > 0; s >>= 1) {
        if (tid < s) r0[tid] = fmaxf(r0[tid], r0[tid + s]);
        __syncthreads();
    }
    const float mx = r0[0];
    __syncthreads();
    float s = 0.0f, sx = 0.0f, sy = 0.0f;
    for (int i = tid; i < 65536; i += 256) {
        float e = expf((row[i] - mx) * 10.0f);
        s += e;
        sx += e * (float)(i & 255);
        sy += e * (float)(i >> 8);
    }
    r0[tid] = s; r1[tid] = sx; r2[tid] = sy;
    __syncthreads();
    for (int st = 128; st > 0; st >>= 1) {
        if (tid < st) { r0[tid] += r0[tid + st]; r1[tid] += r1[tid + st]; r2[tid] += r2[tid + st]; }
        __syncthreads();
    }
    if (tid == 0) {
        coords[2 * bj] = r1[0] / r0[0];
        coords[2 * bj + 1] = r2[0] / r0[0];
    }
}

// ================= bilinear sample (bf16 NHWC feat) + proj =================
__global__ __launch_bounds__(64)
void joint_bf_k(const __hip_bfloat16* __restrict__ fm, const float* __restrict__ coords,
                const float* __restrict__ pw, const float* __restrict__ pb,
                float* __restrict__ jf)
{
    __shared__ float sj[64];
    const int bj = blockIdx.x, b = bj / 33;
    const int tid = threadIdx.x;
    float ix = coords[2 * bj], iy = coords[2 * bj + 1];
    float x0f = fminf(fmaxf(floorf(ix), 0.0f), 255.0f);
    float y0f = fminf(fmaxf(floorf(iy), 0.0f), 255.0f);
    float wx = ix - x0f, wy = iy - y0f;
    int x0 = (int)x0f, y0 = (int)y0f;
    int x1 = min(x0 + 1, 255), y1 = min(y0 + 1, 255);
    const __hip_bfloat16* base = fm + (long)b * 65536 * 64 + tid;
    float v00 = __bfloat162float(base[((long)y0 * 256 + x0) * 64]);
    float v01 = __bfloat162float(base[((long)y0 * 256 + x1) * 64]);
    float v10 = __bfloat162float(base[((long)y1 * 256 + x0) * 64]);
    float v11 = __bfloat162float(base[((long)y1 * 256 + x1) * 64]);
    sj[tid] = v00 * (1 - wx) * (1 - wy) + v01 * wx * (1 - wy)
            + v10 * (1 - wx) * wy + v11 * wx * wy;
    __syncthreads();
    float a = pb[tid];
    for (int k = 0; k < 64; ++k) a = fmaf(sj[k], pw[tid * 64 + k], a);
    jf[(long)bj * 64 + tid] = a;
}

// ================= graph message + GRU =================
__device__ const int d_nbr[33][4] = {
    {0,0,0,0},{1,0,0,0},{2,0,0,0},{3,0,0,0},{4,0,0,0},{5,0,0,0},{6,0,0,0},{7,0,0,0},
    {8,0,0,0},{9,0,0,0},{10,0,0,0},
    {11,12,23,13},{12,11,24,14},{13,11,15,0},{14,12,16,0},{15,13,0,0},{16,14,0,0},
    {17,0,0,0},{18,0,0,0},{19,0,0,0},{20,0,0,0},{21,0,0,0},{22,0,0,0},
    {23,11,24,25},{24,12,23,26},{25,23,27,0},{26,24,28,0},{27,25,0,0},{28,26,0,0},
    {29,0,0,0},{30,0,0,0},{31,0,0,0},{32,0,0,0}};
__device__ const int d_cnt[33] = {1,1,1,1,1,1,1,1,1,1,1,4,4,3,3,2,2,1,1,1,1,1,1,4,4,3,3,2,2,1,1,1,1};

__global__ __launch_bounds__(192)
void gru_k(const float* __restrict__ jf, const float* __restrict__ mw, const float* __restrict__ mb,
           const float* __restrict__ wih, const float* __restrict__ whh,
           const float* __restrict__ bih, const float* __restrict__ bhh,
           float* __restrict__ rbias)
{
    __shared__ float s_mjf[64], s_jf[64], s_msg[64], s_gi[192], s_gh[192], s_ref[64];
    const int bj = blockIdx.x;
    const int b = bj / 33, j = bj % 33;
    const int tid = threadIdx.x;
    if (tid < 64) {
        int cnt = d_cnt[j];
        float s = 0.0f;
        for (int n = 0; n < 4; ++n)
            if (n < cnt) s += jf[((long)b * 33 + d_nbr[j][n]) * 64 + tid];
        s_mjf[tid] = s / (float)cnt;
        s_jf[tid] = jf[(long)bj * 64 + tid];
    }
    __syncthreads();
    if (tid < 64) {
        float a = mb[tid];
        for (int k = 0; k < 64; ++k) a = fmaf(mw[tid * 64 + k], s_mjf[k], a);
        s_msg[tid] = a;
    }
    __syncthreads();
    {
        float a = bih[tid], c = bhh[tid];
        for (int k = 0; k < 64; ++k) {
            a = fmaf(wih[tid * 64 + k], s_msg[k], a);
            c = fmaf(whh[tid * 64 + k], s_jf[k], c);
        }
        s_gi[tid] = a; s_gh[tid] = c;
    }
    __syncthreads();
    if (tid < 64) {
        float r = sigf(s_gi[tid] + s_gh[tid]);
        float z = sigf(s_gi[64 + tid] + s_gh[64 + tid]);
        float n = tanhf(s_gi[128 + tid] + r * s_gh[128 + tid]);
        s_ref[tid] = (1.0f - z) * n + z * s_jf[tid];
    }
    __syncthreads();
    if (tid == 0) {
        float s = 0.0f;
        for (int k = 0; k < 64; ++k) s += s_ref[k];
        rbias[bj] = s * (1.0f / 64.0f);
    }
}

// ================= vis branch =================
__global__ __launch_bounds__(256)
void vispool_bf_k(const __hip_bfloat16* __restrict__ enc, float* __restrict__ p)
{
    int idx = blockIdx.x * 256 + threadIdx.x;  // 65536
    int v = idx & 3, uu = (idx >> 2) & 3, c = (idx >> 4) & 255, b = idx >> 12;
    const __hip_bfloat16* base = enc + (long)b * 64 * 64 * 256 + c;
    float s = 0.0f;
    for (int a = 0; a < 16; ++a)
#pragma unroll
        for (int d = 0; d < 16; ++d)
            s += __bfloat162float(base[((long)(uu * 16 + a) * 64 + (v * 16 + d)) * 256]);
    p[idx] = s * (1.0f / 256.0f);
}

__global__ __launch_bounds__(256)
void visfc1_k(const float* __restrict__ p, const float* __restrict__ w1,
              const float* __restrict__ b1, float* __restrict__ v1)
{
    __shared__ float s_p[4096];
    const int b = blockIdx.x, tid = threadIdx.x;
    for (int i = tid; i < 4096; i += 256) s_p[i] = p[b * 4096 + i];
    __syncthreads();
    float a = b1[tid];
    const float* wr = w1 + (long)tid * 4096;
    for (int k = 0; k < 4096; ++k) a = fmaf(wr[k], s_p[k], a);
    v1[b * 256 + tid] = fmaxf(a, 0.0f);
}

__global__ __launch_bounds__(64)
void visfc2_k(const float* __restrict__ v1, const float* __restrict__ w2,
              const float* __restrict__ b2, float* __restrict__ out)
{
    const int b = blockIdx.x, t = threadIdx.x;
    if (t < 33) {
        float a = b2[t];
        for (int k = 0; k < 256; ++k) a = fmaf(w2[t * 256 + k], v1[b * 256 + k], a);
        out[b * 33 + t] = sigf(a);
    }
}

extern "C" void kernel_launch(void* const* d_in, const int* in_sizes, int n_in,
                              void* d_out, int out_size, void* d_ws, size_t ws_size,
                              hipStream_t stream)
{
    const float* x   = (const float*)d_in[0];
    const float* c1w = (const float*)d_in[1];  const float* c1b = (const float*)d_in[2];
    const float* b1g = (const float*)d_in[3];  const float* b1b = (const float*)d_in[4];
    const float* c2w = (const float*)d_in[5];  const float* c2b = (const float*)d_in[6];
    const float* b2g = (const float*)d_in[7];  const float* b2b = (const float*)d_in[8];
    const float* c3w = (const float*)d_in[9];  const float* c3b = (const float*)d_in[10];
    const float* b3g = (const float*)d_in[11]; const float* b3b = (const float*)d_in[12];
    const float* c4w = (const float*)d_in[13]; const float* c4b = (const float*)d_in[14];
    const float* b4g = (const float*)d_in[15]; const float* b4b = (const float*)d_in[16];
    const float* d1w = (const float*)d_in[17]; const float* d1b = (const float*)d_in[18];
    const float* d2w = (const float*)d_in[19]; const float* d2b = (const float*)d_in[20];
    const float* hw  = (const float*)d_in[21]; const float* hb  = (const float*)d_in[22];
    const float* pw  = (const float*)d_in[23]; const float* pb  = (const float*)d_in[24];
    const float* mw  = (const float*)d_in[25]; const float* mb  = (const float*)d_in[26];
    const float* wih = (const float*)d_in[27]; const float* whh = (const float*)d_in[28];
    const float* bih = (const float*)d_in[29]; const float* bhh = (const float*)d_in[30];
    const float* rw  = (const float*)d_in[31]; const float* rb  = (const float*)d_in[32];
    const float* v1w = (const float*)d_in[33]; const float* v1b = (const float*)d_in[34];
    const float* v2w = (const float*)d_in[35]; const float* v2b = (const float*)d_in[36];

    // ---- lifetime-packed workspace (byte offsets; peak ~442 MiB, proven ws >= 474 MiB) ----
    char* ws = (char*)d_ws;
    __hip_bfloat16* ENC    = (__hip_bfloat16*)(ws + 0L);           // 33.5 MB  [conv4..vis]
    __hip_bfloat16* FEAT   = (__hip_bfloat16*)(ws + 33554432L);    // 134 MB   [dc2..joint]
    __hip_bfloat16* HEADB  = (__hip_bfloat16*)(ws + 167772160L);   // 134 MB   [head..refine]
    float*          INITHM = (float*)(ws + 301989888L);            // 138 MB   [head..softargmax]
    __hip_bfloat16* H1     = (__hip_bfloat16*)(ws + 301989888L);   // 67 MB    [conv1..conv2]
    __hip_bfloat16* H2     = (__hip_bfloat16*)(ws + 33554432L);    // 134 MB   [conv2..pool1]
    __hip_bfloat16* P1     = (__hip_bfloat16*)(ws + 167772160L);   // 33.5 MB  [pool1..conv3]
    __hip_bfloat16* H3     = (__hip_bfloat16*)(ws + 201326592L);   // 67 MB    [conv3..pool2]
    __hip_bfloat16* P2     = (__hip_bfloat16*)(ws + 268435456L);   // 16.8 MB  [pool2..conv4]
    __hip_bfloat16* F      = (__hip_bfloat16*)(ws + 167772160L);   // 67 MB    [dc1..dc2]
    char* SM = ws + 440401920L;
    __hip_bfloat16* W2B = (__hip_bfloat16*)(SM + 0);
    __hip_bfloat16* W3B = (__hip_bfloat16*)(SM + 40960);
    __hip_bfloat16* W4B = (__hip_bfloat16*)(SM + 190464);
    __hip_bfloat16* WRB = (__hip_bfloat16*)(SM + 782336);
    __hip_bfloat16* WHB = (__hip_bfloat16*)(SM + 856064);
    __hip_bfloat16* WD1 = (__hip_bfloat16*)(SM + 866304);
    __hip_bfloat16* WD2 = (__hip_bfloat16*)(SM + 1128448);
    float* CO = (float*)(SM + 1196032);
    float* JF = (float*)(SM + 1200384);
    float* RB = (float*)(SM + 1335552);
    float* P  = (float*)(SM + 1337856);
    float* V1 = (float*)(SM + 1600000);

    float* out_hm  = (float*)d_out;        // (16,33,256,256)
    float* out_vis = out_hm + 34603008L;   // (16,33)

    // ---- weight repacks ----
    repack_conv_w_k<<<(9*64*32 + 255)/256, 256, 0, stream>>>(c2w, W2B, 9, 64, 32, 64, 32);
    repack_conv_w_k<<<(9*128*64 + 255)/256, 256, 0, stream>>>(c3w, W3B, 9, 128, 64, 128, 64);
    repack_conv_w_k<<<(9*256*128 + 255)/256, 256, 0, stream>>>(c4w, W4B, 9, 256, 128, 256, 128);
    repack_conv_w_k<<<(9*64*64 + 255)/256, 256, 0, stream>>>(rw, WRB, 9, 33, 33, 64, 64);
    repack_conv_w_k<<<(1*64*64 + 255)/256, 256, 0, stream>>>(hw, WHB, 1, 33, 64, 64, 64);
    repack_deconv_w_k<<<(4*128*256 + 255)/256, 256, 0, stream>>>(d1w, WD1, 128, 256);
    repack_deconv_w_k<<<(4*64*128 + 255)/256, 256, 0, stream>>>(d2w, WD2, 64, 128);

    // 1) conv1 3->32 @256 -> H1 (bf16 nhwc)
    conv1_k<<<dim3(4, 16, 64), 256, 0, stream>>>(x, c1w, c1b, b1g, b1b, H1);
    // 2) conv2 32->64 @256 (MFMA) -> H2
    mfma_conv_k<0><<<dim3(256, 1, 16), 256, 0, stream>>>(
        H1, W2B, c2b, b2g, b2b, nullptr, H2, nullptr, 256, 256, 32, 64, 1, 4);
    // 3) pool -> P1 (128x128x64)
    maxpool_bf_k<<<8192, 256, 0, stream>>>(H2, P1, 128, 128, 64, 2097152L);
    // 4) conv3 64->128 @128 -> H3
    mfma_conv_k<0><<<dim3(64, 1, 32), 256, 0, stream>>>(
        P1, W3B, c3b, b3g, b3b, nullptr, H3, nullptr, 128, 128, 64, 128, 2, 2);
    // 5) pool -> P2 (64x64x128)
    maxpool_bf_k<<<4096, 256, 0, stream>>>(H3, P2, 64, 64, 128, 1048576L);
    // 6) conv4 128->256 @64 -> ENC
    mfma_conv_k<0><<<dim3(16, 1, 64), 256, 0, stream>>>(
        P2, W4B, c4b, b4g, b4b, nullptr, ENC, nullptr, 64, 64, 128, 256, 4, 1);
    // 7) dc1 256->128 (64->128 up) -> F
    mfma_deconv_k<<<dim3(16, 1, 32), 256, 0, stream>>>(
        ENC, WD1, d1b, F, 64, 64, 256, 128, 2, 1);
    // 8) dc2 128->64 (128->256 up) -> FEAT
    mfma_deconv_k<<<dim3(64, 1, 16), 256, 0, stream>>>(
        F, WD2, d2b, FEAT, 128, 128, 128, 64, 1, 2);
    // 9) head 1x1 + sigmoid -> HEADB (bf16 nhwc, pad->0) + INITHM (f32 nchw)
    mfma_conv_k<1><<<dim3(256, 1, 16), 256, 66560, stream>>>(
        FEAT, WHB, hb, nullptr, nullptr, nullptr, HEADB, INITHM, 256, 256, 64, 64, 1, 4);
    // 10) soft-argmax
    softargmax_k<<<528, 256, 0, stream>>>(INITHM, CO);
    // 11) bilinear + proj
    joint_bf_k<<<528, 64, 0, stream>>>(FEAT, CO, pw, pb, JF);
    // 12) message + GRU -> refined_bias
    gru_k<<<528, 192, 0, stream>>>(JF, mw, mb, wih, whh, bih, bhh, RB);
    // 13) refine 33->33 @256 (padded 64) + bias + sigmoid -> out_hm (f32 nchw)
    mfma_conv_k<2><<<dim3(256, 1, 16), 256, 66560, stream>>>(
        HEADB, WRB, rb, nullptr, nullptr, RB, nullptr, out_hm, 256, 256, 64, 64, 1, 4);
    // 14) vis pool -> P (16,4096)
    vispool_bf_k<<<256, 256, 0, stream>>>(ENC, P);
    // 15) fc1 + relu
    visfc1_k<<<16, 256, 0, stream>>>(P, v1w, v1b, V1);
    // 16) fc2 + sigmoid
    visfc2_k<<<16, 64, 0, stream>>>(V1, v2w, v2b, out_vis);
}

// Round 8
// 1562.462 us; speedup vs baseline: 3.6088x; 1.1652x over previous
//
#include <hip/hip_runtime.h>
#include <hip/hip_bf16.h>
#include <math.h>

#define BN_RS 0.99999500003749977f  // 1/sqrt(1 + 1e-5)

typedef __attribute__((ext_vector_type(8))) __bf16 bf16x8;
typedef __attribute__((ext_vector_type(4))) float f32x4;

union U16 { uint4 u; bf16x8 v; __hip_bfloat16 h[8]; };

__device__ __forceinline__ float sigf(float v) { return 1.0f / (1.0f + expf(-v)); }

// ================= weight repack =================
__global__ __launch_bounds__(256)
void repack_conv_w_k(const float* __restrict__ w, __hip_bfloat16* __restrict__ wb,
                     int taps, int Co, int Ci, int CoT, int Kp)
{
    int i = blockIdx.x * 256 + threadIdx.x;
    int tot = taps * CoT * Kp;
    if (i >= tot) return;
    int k = i % Kp, n = (i / Kp) % CoT, t = i / (Kp * CoT);
    float v = (n < Co && k < Ci) ? w[((long)n * Ci + k) * taps + t] : 0.0f;
    wb[i] = __float2bfloat16(v);
}
__global__ __launch_bounds__(256)
void repack_deconv_w_k(const float* __restrict__ w, __hip_bfloat16* __restrict__ wb,
                       int Co, int Ci)
{
    int i = blockIdx.x * 256 + threadIdx.x;
    int tot = 4 * Co * Ci;
    if (i >= tot) return;
    int k = i % Ci, n = (i / Ci) % Co, q = i / (Ci * Co);
    wb[i] = __float2bfloat16(w[((long)k * Co + n) * 4 + q]);
}

// ================= zero the 1-px halo of a padded NHWC buffer =================
__global__ __launch_bounds__(256)
void zero_halo_k(__hip_bfloat16* __restrict__ buf, int H, int W, int C, int B)
{
    const int P = W + 2;
    const long per = (long)(2 * P + 2 * H) * C;
    long idx = (long)blockIdx.x * 256 + threadIdx.x;
    if (idx >= per * B) return;
    int b = (int)(idx / per);
    long r = idx % per;
    long off;
    if (r < (long)2 * P * C) {
        int row = (r >= (long)P * C) ? (H + 1) : 0;
        long r2 = r % ((long)P * C);
        off = (((long)b * (H + 2) + row) * P) * C + r2;
    } else {
        long r2 = r - (long)2 * P * C;
        int row = 1 + (int)(r2 / (2 * C));
        int side = (int)((r2 / C) & 1);
        int ch = (int)(r2 % C);
        off = (((long)b * (H + 2) + row) * P + (side ? (W + 1) : 0)) * C + ch;
    }
    buf[off] = __float2bfloat16(0.0f);
}

// ================= conv1 (3->32, scalar fp32, writes bf16 NHWC padded-interior) =================
__global__ __launch_bounds__(256)
void conv1_k(const float* __restrict__ x, const float* __restrict__ w,
             const float* __restrict__ cb, const float* __restrict__ g,
             const float* __restrict__ bb, __hip_bfloat16* __restrict__ out)
{
    __shared__ float sw[216];
    const int tid = threadIdx.x;
    const int b = blockIdx.z >> 2, cg = blockIdx.z & 3, co0 = cg * 8;
    for (int i = tid; i < 216; i += 256) {
        int t = i % 9, co = (i / 9) % 8, ci = i / 72;
        sw[i] = w[((co0 + co) * 3 + ci) * 9 + t];
    }
    __syncthreads();
    const int tx = tid & 15, ty = tid >> 4;
    const int y = blockIdx.y * 16 + ty;
    const int xs = blockIdx.x * 64 + tx;
    float acc[4][8];
#pragma unroll
    for (int p = 0; p < 4; ++p)
#pragma unroll
        for (int c = 0; c < 8; ++c) acc[p][c] = 0.0f;
    for (int ci = 0; ci < 3; ++ci) {
        const float* plane = x + ((long)b * 3 + ci) * 65536;
#pragma unroll
        for (int t = 0; t < 9; ++t) {
            const int dy = t / 3 - 1, dx = t % 3 - 1;
            const int yy = y + dy;
            if ((unsigned)yy < 256u) {
                const float* row = plane + yy * 256;
                float wsr[8];
#pragma unroll
                for (int c = 0; c < 8; ++c) wsr[c] = sw[ci * 72 + c * 9 + t];
#pragma unroll
                for (int p = 0; p < 4; ++p) {
                    const int xx = xs + p * 16 + dx;
                    const float v = ((unsigned)xx < 256u) ? row[xx] : 0.0f;
#pragma unroll
                    for (int c = 0; c < 8; ++c) acc[p][c] = fmaf(v, wsr[c], acc[p][c]);
                }
            }
        }
    }
#pragma unroll
    for (int p = 0; p < 4; ++p) {
        U16 o;
#pragma unroll
        for (int c = 0; c < 8; ++c) {
            const int cc = co0 + c;
            float v = fmaxf(acc[p][c] + cb[cc], 0.0f) * (g[cc] * BN_RS) + bb[cc];
            o.h[c] = __float2bfloat16(v);
        }
        *(uint4*)(void*)(out + ((long)b * 2130048L + ((long)y * 258 + xs + p * 16) * 32) + co0) = o.u;
    }
}

// ================= MFMA conv (implicit GEMM, halo-padded input, no bounds checks) ==========
// MODE 0: 3x3 + relu/BN -> bf16 NHWC (unpadded out)
// MODE 1: 1x1 head + sigmoid -> bf16 NHWC padded-interior (c<48, pad->0) + f32 NCHW
// MODE 2: 3x3 refine + cbias + ebias + sigmoid -> f32 NCHW
template<int MODE, int NI>
__global__ __launch_bounds__(256)
void mfma_conv_k(const __hip_bfloat16* __restrict__ in,   // interior origin (padded) / plain (MODE 1)
                 const __hip_bfloat16* __restrict__ wb,
                 const float* __restrict__ cbias,
                 const float* __restrict__ bng, const float* __restrict__ bnb,
                 const float* __restrict__ ebias,
                 __hip_bfloat16* __restrict__ out_bf, float* __restrict__ out_f32,
                 int H, int W, int Cin, int PIT, long bstride, long obstride, int OPIT,
                 int CoutT, int CG, int S)
{
    extern __shared__ float ltr[];  // MODE 1/2: 4 waves x 48ch x 67px f32
    const int tid = threadIdx.x;
    const int wid = tid >> 6, lane = tid & 63;
    const int ln = lane & 15, kg = lane >> 4;
    const int u = blockIdx.x * 4 + wid;
    const int y = u / S, x0 = (u % S) * 64;
    const int b = blockIdx.z / CG, cg = blockIdx.z % CG;
    const int co0 = cg * 64;
    const int KC = Cin >> 5;

    f32x4 acc[4][NI];
#pragma unroll
    for (int i = 0; i < 4; ++i)
#pragma unroll
        for (int j = 0; j < NI; ++j) acc[i][j] = f32x4{0.f, 0.f, 0.f, 0.f};

    constexpr int NT = (MODE == 1) ? 1 : 9;
    for (int kc = 0; kc < KC; ++kc) {
        const int kofs = kc * 32 + kg * 8;
#pragma unroll
        for (int t = 0; t < NT; ++t) {
            const int dy = (MODE == 1) ? 0 : (t / 3 - 1);
            const int dx = (MODE == 1) ? 0 : (t % 3 - 1);
            bf16x8 wfr[NI];
#pragma unroll
            for (int ni = 0; ni < NI; ++ni)
                wfr[ni] = *(const bf16x8*)(const void*)(wb + ((long)t * CoutT + co0 + ni * 16 + ln) * Cin + kofs);
            U16 av[4];
            const long rowb = (long)b * bstride + (long)(y + dy) * PIT * Cin + kofs;
#pragma unroll
            for (int mi = 0; mi < 4; ++mi)
                av[mi].u = *(const uint4*)(const void*)(in + rowb + (long)(x0 + mi * 16 + ln + dx) * Cin);
#pragma unroll
            for (int mi = 0; mi < 4; ++mi)
#pragma unroll
                for (int ni = 0; ni < NI; ++ni)
                    acc[mi][ni] = __builtin_amdgcn_mfma_f32_16x16x32_bf16(av[mi].v, wfr[ni], acc[mi][ni], 0, 0, 0);
        }
    }

    if constexpr (MODE == 0) {
#pragma unroll
        for (int mi = 0; mi < 4; ++mi) {
#pragma unroll
            for (int r = 0; r < 4; ++r) {
                const int px = x0 + mi * 16 + kg * 4 + r;
                const long pb = (long)b * obstride + ((long)y * OPIT + px) * CoutT + co0;
#pragma unroll
                for (int ni = 0; ni < NI; ++ni) {
                    const int c = co0 + ni * 16 + ln;
                    float v = acc[mi][ni][r] + cbias[c];
                    v = fmaxf(v, 0.0f) * (bng[c] * BN_RS) + bnb[c];
                    out_bf[pb + ni * 16 + ln] = __float2bfloat16(v);
                }
            }
        }
    } else {
        float* wt = ltr + wid * (48 * 67);
#pragma unroll
        for (int mi = 0; mi < 4; ++mi) {
#pragma unroll
            for (int r = 0; r < 4; ++r) {
                const int pxl = mi * 16 + kg * 4 + r;
#pragma unroll
                for (int ni = 0; ni < NI; ++ni) {
                    const int c = ni * 16 + ln;  // co0 == 0 in these modes
                    float v = acc[mi][ni][r];
                    if constexpr (MODE == 1) {
                        v = sigf(v + ((c < 33) ? cbias[c] : 0.0f));
                        out_bf[(long)b * obstride + ((long)y * OPIT + x0 + pxl) * CoutT + c] =
                            (c < 33) ? __float2bfloat16(v) : __float2bfloat16(0.0f);
                    } else {
                        float eb = (c < 33) ? (cbias[c] + ebias[b * 33 + c]) : 0.0f;
                        v = sigf(v + eb);
                    }
                    wt[c * 67 + pxl] = v;
                }
            }
        }
        // wave-local transpose readback (each wave reads only its own LDS region)
        const long o32 = ((long)b * 33) * H * W + (long)y * W + x0 + lane;
        for (int c = 0; c < 33; ++c)
            out_f32[o32 + (long)c * H * W] = wt[c * 67 + lane];
    }
}

// ================= MFMA deconv 2x2 + ReLU (bf16 NHWC out, 2x upsample) =================
__global__ __launch_bounds__(256)
void mfma_deconv_k(const __hip_bfloat16* __restrict__ in,
                   const __hip_bfloat16* __restrict__ wb,
                   const float* __restrict__ bias,
                   __hip_bfloat16* __restrict__ out,
                   int H, int W, int Cin, int CoutT, int CG, int S)
{
    const int tid = threadIdx.x;
    const int wid = tid >> 6, lane = tid & 63;
    const int ln = lane & 15, kg = lane >> 4;
    const int u = blockIdx.x * 4 + wid;
    const int y = u / S, x0 = (u % S) * 64;
    const int b = blockIdx.z / CG, cg = blockIdx.z % CG;
    const int co0 = cg * 64;
    const int KC = Cin >> 5;
    const long inb = (long)b * H * W * Cin;
    const int W2 = W * 2;
    const long ob = (long)b * 4 * H * W * CoutT;

    for (int q = 0; q < 4; ++q) {
        const int dy = q >> 1, dx = q & 1;
        f32x4 acc[4][4];
#pragma unroll
        for (int i = 0; i < 4; ++i)
#pragma unroll
            for (int j = 0; j < 4; ++j) acc[i][j] = f32x4{0.f, 0.f, 0.f, 0.f};
        for (int kc = 0; kc < KC; ++kc) {
            const int kofs = kc * 32 + kg * 8;
            bf16x8 wfr[4];
            U16 av[4];
#pragma unroll
            for (int ni = 0; ni < 4; ++ni)
                wfr[ni] = *(const bf16x8*)(const void*)(wb + ((long)q * CoutT + co0 + ni * 16 + ln) * Cin + kofs);
#pragma unroll
            for (int mi = 0; mi < 4; ++mi)
                av[mi].u = *(const uint4*)(const void*)(in + inb + ((long)y * W + x0 + mi * 16 + ln) * Cin + kofs);
#pragma unroll
            for (int mi = 0; mi < 4; ++mi)
#pragma unroll
                for (int ni = 0; ni < 4; ++ni)
                    acc[mi][ni] = __builtin_amdgcn_mfma_f32_16x16x32_bf16(av[mi].v, wfr[ni], acc[mi][ni], 0, 0, 0);
        }
#pragma unroll
        for (int mi = 0; mi < 4; ++mi) {
#pragma unroll
            for (int r = 0; r < 4; ++r) {
                const int xl = x0 + mi * 16 + kg * 4 + r;
                const long pb = ob + ((long)(2 * y + dy) * W2 + 2 * xl + dx) * CoutT + co0;
#pragma unroll
                for (int ni = 0; ni < 4; ++ni) {
                    const int c = co0 + ni * 16 + ln;
                    float v = fmaxf(acc[mi][ni][r] + bias[c], 0.0f);
                    out[pb + ni * 16 + ln] = __float2bfloat16(v);
                }
            }
        }
    }
}

// ================= maxpool 2x2 on bf16 NHWC (padded-interior output) =================
__global__ __launch_bounds__(256)
void maxpool_bf_k(const __hip_bfloat16* __restrict__ in, __hip_bfloat16* __restrict__ out,
                  int Ho, int Wo, int C, long total, int OPIT, long obstride)
{
    long idx = (long)blockIdx.x * 256 + threadIdx.x;
    if (idx >= total) return;
    const int ng = C >> 3;
    const int cg = (int)(idx % ng);
    long pix = idx / ng;
    const int xo = (int)(pix % Wo); pix /= Wo;
    const int yo = (int)(pix % Ho);
    const int b = (int)(pix / Ho);
    const int Wi = Wo * 2;
    const __hip_bfloat16* p = in + (((long)b * 2 * Ho + 2 * yo) * Wi + 2 * xo) * C + cg * 8;
    U16 a0, a1, a2, a3, o;
    a0.u = *(const uint4*)(const void*)p;
    a1.u = *(const uint4*)(const void*)(p + C);
    a2.u = *(const uint4*)(const void*)(p + (long)Wi * C);
    a3.u = *(const uint4*)(const void*)(p + (long)Wi * C + C);
#pragma unroll
    for (int j = 0; j < 8; ++j) {
        float m = fmaxf(fmaxf(__bfloat162float(a0.h[j]), __bfloat162float(a1.h[j])),
                        fmaxf(__bfloat162float(a2.h[j]), __bfloat162float(a3.h[j])));
        o.h[j] = __float2bfloat16(m);
    }
    *(uint4*)(void*)(out + (long)b * obstride + ((long)yo * OPIT + xo) * C + cg * 8) = o.u;
}

// ================= soft-argmax (f32 NCHW heatmap) =================
__global__ __launch_bounds__(256)
void softargmax_k(const float* __restrict__ hm, float* __restrict__ coords)
{
    __shared__ float r0[256], r1[256], r2[256];
    const int bj = blockIdx.x;
    const int tid = threadIdx.x;
    const float* row = hm + (long)bj * 65536;
    float m = -1e30f;
    for (int i = tid; i < 65536; i += 256) m = fmaxf(m, row[i]);
    r0[tid] = m;
    __syncthreads();
    for (int s = 128; s > 0; s >>= 1) {
        if (tid < s) r0[tid] = fmaxf(r0[tid], r0[tid + s]);
        __syncthreads();
    }
    const float mx = r0[0];
    __syncthreads();
    float s = 0.0f, sx = 0.0f, sy = 0.0f;
    for (int i = tid; i < 65536; i += 256) {
        float e = expf((row[i] - mx) * 10.0f);
        s += e;
        sx += e * (float)(i & 255);
        sy += e * (float)(i >> 8);
    }
    r0[tid] = s; r1[tid] = sx; r2[tid] = sy;
    __syncthreads();
    for (int st = 128; st > 0; st >>= 1) {
        if (tid < st) { r0[tid] += r0[tid + st]; r1[tid] += r1[tid + st]; r2[tid] += r2[tid + st]; }
        __syncthreads();
    }
    if (tid == 0) {
        coords[2 * bj] = r1[0] / r0[0];
        coords[2 * bj + 1] = r2[0] / r0[0];
    }
}

// ================= bilinear sample (bf16 NHWC feat) + proj =================
__global__ __launch_bounds__(64)
void joint_bf_k(const __hip_bfloat16* __restrict__ fm, const float* __restrict__ coords,
                const float* __restrict__ pw, const float* __restrict__ pb,
                float* __restrict__ jf)
{
    __shared__ float sj[64];
    const int bj = blockIdx.x, b = bj / 33;
    const int tid = threadIdx.x;
    float ix = coords[2 * bj], iy = coords[2 * bj + 1];
    float x0f = fminf(fmaxf(floorf(ix), 0.0f), 255.0f);
    float y0f = fminf(fmaxf(floorf(iy), 0.0f), 255.0f);
    float wx = ix - x0f, wy = iy - y0f;
    int x0 = (int)x0f, y0 = (int)y0f;
    int x1 = min(x0 + 1, 255), y1 = min(y0 + 1, 255);
    const __hip_bfloat16* base = fm + (long)b * 65536 * 64 + tid;
    float v00 = __bfloat162float(base[((long)y0 * 256 + x0) * 64]);
    float v01 = __bfloat162float(base[((long)y0 * 256 + x1) * 64]);
    float v10 = __bfloat162float(base[((long)y1 * 256 + x0) * 64]);
    float v11 = __bfloat162float(base[((long)y1 * 256 + x1) * 64]);
    sj[tid] = v00 * (1 - wx) * (1 - wy) + v01 * wx * (1 - wy)
            + v10 * (1 - wx) * wy + v11 * wx * wy;
    __syncthreads();
    float a = pb[tid];
    for (int k = 0; k < 64; ++k) a = fmaf(sj[k], pw[tid * 64 + k], a);
    jf[(long)bj * 64 + tid] = a;
}

// ================= graph message + GRU =================
__device__ const int d_nbr[33][4] = {
    {0,0,0,0},{1,0,0,0},{2,0,0,0},{3,0,0,0},{4,0,0,0},{5,0,0,0},{6,0,0,0},{7,0,0,0},
    {8,0,0,0},{9,0,0,0},{10,0,0,0},
    {11,12,23,13},{12,11,24,14},{13,11,15,0},{14,12,16,0},{15,13,0,0},{16,14,0,0},
    {17,0,0,0},{18,0,0,0},{19,0,0,0},{20,0,0,0},{21,0,0,0},{22,0,0,0},
    {23,11,24,25},{24,12,23,26},{25,23,27,0},{26,24,28,0},{27,25,0,0},{28,26,0,0},
    {29,0,0,0},{30,0,0,0},{31,0,0,0},{32,0,0,0}};
__device__ const int d_cnt[33] = {1,1,1,1,1,1,1,1,1,1,1,4,4,3,3,2,2,1,1,1,1,1,1,4,4,3,3,2,2,1,1,1,1};

__global__ __launch_bounds__(192)
void gru_k(const float* __restrict__ jf, const float* __restrict__ mw, const float* __restrict__ mb,
           const float* __restrict__ wih, const float* __restrict__ whh,
           const float* __restrict__ bih, const float* __restrict__ bhh,
           float* __restrict__ rbias)
{
    __shared__ float s_mjf[64], s_jf[64], s_msg[64], s_gi[192], s_gh[192], s_ref[64];
    const int bj = blockIdx.x;
    const int b = bj / 33, j = bj % 33;
    const int tid = threadIdx.x;
    if (tid < 64) {
        int cnt = d_cnt[j];
        float s = 0.0f;
        for (int n = 0; n < 4; ++n)
            if (n < cnt) s += jf[((long)b * 33 + d_nbr[j][n]) * 64 + tid];
        s_mjf[tid] = s / (float)cnt;
        s_jf[tid] = jf[(long)bj * 64 + tid];
    }
    __syncthreads();
    if (tid < 64) {
        float a = mb[tid];
        for (int k = 0; k < 64; ++k) a = fmaf(mw[tid * 64 + k], s_mjf[k], a);
        s_msg[tid] = a;
    }
    __syncthreads();
    {
        float a = bih[tid], c = bhh[tid];
        for (int k = 0; k < 64; ++k) {
            a = fmaf(wih[tid * 64 + k], s_msg[k], a);
            c = fmaf(whh[tid * 64 + k], s_jf[k], c);
        }
        s_gi[tid] = a; s_gh[tid] = c;
    }
    __syncthreads();
    if (tid < 64) {
        float r = sigf(s_gi[tid] + s_gh[tid]);
        float z = sigf(s_gi[64 + tid] + s_gh[64 + tid]);
        float n = tanhf(s_gi[128 + tid] + r * s_gh[128 + tid]);
        s_ref[tid] = (1.0f - z) * n + z * s_jf[tid];
    }
    __syncthreads();
    if (tid == 0) {
        float s = 0.0f;
        for (int k = 0; k < 64; ++k) s += s_ref[k];
        rbias[bj] = s * (1.0f / 64.0f);
    }
}

// ================= vis branch =================
__global__ __launch_bounds__(256)
void vispool_bf_k(const __hip_bfloat16* __restrict__ enc, float* __restrict__ p)
{
    int idx = blockIdx.x * 256 + threadIdx.x;  // 65536
    int v = idx & 3, uu = (idx >> 2) & 3, c = (idx >> 4) & 255, b = idx >> 12;
    const __hip_bfloat16* base = enc + (long)b * 64 * 64 * 256 + c;
    float s = 0.0f;
    for (int a = 0; a < 16; ++a)
#pragma unroll
        for (int d = 0; d < 16; ++d)
            s += __bfloat162float(base[((long)(uu * 16 + a) * 64 + (v * 16 + d)) * 256]);
    p[idx] = s * (1.0f / 256.0f);
}

__global__ __launch_bounds__(256)
void visfc1_k(const float* __restrict__ p, const float* __restrict__ w1,
              const float* __restrict__ b1, float* __restrict__ v1)
{
    __shared__ float s_p[4096];
    const int b = blockIdx.x, tid = threadIdx.x;
    for (int i = tid; i < 4096; i += 256) s_p[i] = p[b * 4096 + i];
    __syncthreads();
    float a = b1[tid];
    const float* wr = w1 + (long)tid * 4096;
    for (int k = 0; k < 4096; ++k) a = fmaf(wr[k], s_p[k], a);
    v1[b * 256 + tid] = fmaxf(a, 0.0f);
}

__global__ __launch_bounds__(64)
void visfc2_k(const float* __restrict__ v1, const float* __restrict__ w2,
              const float* __restrict__ b2, float* __restrict__ out)
{
    const int b = blockIdx.x, t = threadIdx.x;
    if (t < 33) {
        float a = b2[t];
        for (int k = 0; k < 256; ++k) a = fmaf(w2[t * 256 + k], v1[b * 256 + k], a);
        out[b * 33 + t] = sigf(a);
    }
}

extern "C" void kernel_launch(void* const* d_in, const int* in_sizes, int n_in,
                              void* d_out, int out_size, void* d_ws, size_t ws_size,
                              hipStream_t stream)
{
    const float* x   = (const float*)d_in[0];
    const float* c1w = (const float*)d_in[1];  const float* c1b = (const float*)d_in[2];
    const float* b1g = (const float*)d_in[3];  const float* b1b = (const float*)d_in[4];
    const float* c2w = (const float*)d_in[5];  const float* c2b = (const float*)d_in[6];
    const float* b2g = (const float*)d_in[7];  const float* b2b = (const float*)d_in[8];
    const float* c3w = (const float*)d_in[9];  const float* c3b = (const float*)d_in[10];
    const float* b3g = (const float*)d_in[11]; const float* b3b = (const float*)d_in[12];
    const float* c4w = (const float*)d_in[13]; const float* c4b = (const float*)d_in[14];
    const float* b4g = (const float*)d_in[15]; const float* b4b = (const float*)d_in[16];
    const float* d1w = (const float*)d_in[17]; const float* d1b = (const float*)d_in[18];
    const float* d2w = (const float*)d_in[19]; const float* d2b = (const float*)d_in[20];
    const float* hw  = (const float*)d_in[21]; const float* hb  = (const float*)d_in[22];
    const float* pw  = (const float*)d_in[23]; const float* pb  = (const float*)d_in[24];
    const float* mw  = (const float*)d_in[25]; const float* mb  = (const float*)d_in[26];
    const float* wih = (const float*)d_in[27]; const float* whh = (const float*)d_in[28];
    const float* bih = (const float*)d_in[29]; const float* bhh = (const float*)d_in[30];
    const float* rw  = (const float*)d_in[31]; const float* rb  = (const float*)d_in[32];
    const float* v1w = (const float*)d_in[33]; const float* v1b = (const float*)d_in[34];
    const float* v2w = (const float*)d_in[35]; const float* v2b = (const float*)d_in[36];

    // ---- lifetime-packed workspace (peak ~444 MB, proven ws >= 474 MB) ----
    // Padded buffers carry a 1-px halo: pitch = W+2, interior origin = base + (PIT+1)*C.
    char* ws = (char*)d_ws;
    __hip_bfloat16* ENC  = (__hip_bfloat16*)(ws + 0L);             // 33.5 MB [conv4..vis]
    __hip_bfloat16* R1   = (__hip_bfloat16*)(ws + 33554432L);      // H1 -> P1 -> FEAT
    __hip_bfloat16* R2   = (__hip_bfloat16*)(ws + 167772160L);     // H3 -> F -> HEADB
    char*           R3c  = ws + 304095232L;                        // P2 -> INITHM
    char* SM = ws + 442507264L;

    __hip_bfloat16* H1B = R1;                 __hip_bfloat16* H1I = R1 + 8288;    // 258p,C32
    __hip_bfloat16* P1B = R1;                 __hip_bfloat16* P1I = R1 + 8384;    // 130p,C64
    __hip_bfloat16* FEAT = R1;                                                    // 256,C64 plain
    __hip_bfloat16* H3  = R2;                                                     // 128,C128 plain
    __hip_bfloat16* F   = R2;                                                     // 128,C128 plain
    __hip_bfloat16* HDB = R2;                 __hip_bfloat16* HDI = R2 + 16576;   // 258p,C64
    __hip_bfloat16* P2B = (__hip_bfloat16*)R3c; __hip_bfloat16* P2I = P2B + 8576; // 66p,C128
    float*          INITHM = (float*)R3c;                                         // 138 MB

    __hip_bfloat16* W2B = (__hip_bfloat16*)(SM + 0);
    __hip_bfloat16* W3B = (__hip_bfloat16*)(SM + 36864);
    __hip_bfloat16* W4B = (__hip_bfloat16*)(SM + 184320);
    __hip_bfloat16* WRB = (__hip_bfloat16*)(SM + 774144);
    __hip_bfloat16* WHB = (__hip_bfloat16*)(SM + 847872);
    __hip_bfloat16* WD1 = (__hip_bfloat16*)(SM + 856064);
    __hip_bfloat16* WD2 = (__hip_bfloat16*)(SM + 1118208);
    float* CO = (float*)(SM + 1183744);
    float* JF = (float*)(SM + 1187968);
    float* RB = (float*)(SM + 1323136);
    float* P  = (float*)(SM + 1325248);
    float* V1 = (float*)(SM + 1587392);

    float* out_hm  = (float*)d_out;        // (16,33,256,256)
    float* out_vis = out_hm + 34603008L;   // (16,33)
    __hip_bfloat16* H2 = (__hip_bfloat16*)d_out;  // scratch: conv2 out (134 MB <= 138 MB), dead before refine

    // ---- weight repacks ----
    repack_conv_w_k<<<(9*64*32 + 255)/256, 256, 0, stream>>>(c2w, W2B, 9, 64, 32, 64, 32);
    repack_conv_w_k<<<(9*128*64 + 255)/256, 256, 0, stream>>>(c3w, W3B, 9, 128, 64, 128, 64);
    repack_conv_w_k<<<(9*256*128 + 255)/256, 256, 0, stream>>>(c4w, W4B, 9, 256, 128, 256, 128);
    repack_conv_w_k<<<(9*64*64 + 255)/256, 256, 0, stream>>>(rw, WRB, 9, 33, 33, 64, 64);
    repack_conv_w_k<<<(1*64*64 + 255)/256, 256, 0, stream>>>(hw, WHB, 1, 33, 64, 64, 64);
    repack_deconv_w_k<<<(4*128*256 + 255)/256, 256, 0, stream>>>(d1w, WD1, 128, 256);
    repack_deconv_w_k<<<(4*64*128 + 255)/256, 256, 0, stream>>>(d2w, WD2, 64, 128);

    // halo zeroing (H1 now; P2's region untouched until pool2, zero now too)
    zero_halo_k<<<(526336 + 255)/256, 256, 0, stream>>>(H1B, 256, 256, 32, 16);
    zero_halo_k<<<(532480 + 255)/256, 256, 0, stream>>>(P2B, 64, 64, 128, 16);

    // 1) conv1 3->32 @256 -> H1 (bf16 nhwc, padded)
    conv1_k<<<dim3(4, 16, 64), 256, 0, stream>>>(x, c1w, c1b, b1g, b1b, H1I);
    // 2) conv2 32->64 @256 -> H2 (d_out scratch, plain nhwc)
    mfma_conv_k<0, 4><<<dim3(256, 1, 16), 256, 0, stream>>>(
        H1I, W2B, c2b, b2g, b2b, nullptr, H2, nullptr,
        256, 256, 32, 258, 2130048L, 4194304L, 256, 64, 1, 4);
    // 3) pool -> P1 (padded; zero its halo first — shares R1 with H1, now dead)
    zero_halo_k<<<(528384 + 255)/256, 256, 0, stream>>>(P1B, 128, 128, 64, 16);
    maxpool_bf_k<<<8192, 256, 0, stream>>>(H2, P1I, 128, 128, 64, 2097152L, 130, 1081600L);
    // 4) conv3 64->128 @128 -> H3 (plain)
    mfma_conv_k<0, 4><<<dim3(64, 1, 32), 256, 0, stream>>>(
        P1I, W3B, c3b, b3g, b3b, nullptr, H3, nullptr,
        128, 128, 64, 130, 1081600L, 2097152L, 128, 128, 2, 2);
    // 5) pool -> P2 (padded)
    maxpool_bf_k<<<4096, 256, 0, stream>>>(H3, P2I, 64, 64, 128, 1048576L, 66, 557568L);
    // 6) conv4 128->256 @64 -> ENC (plain)
    mfma_conv_k<0, 4><<<dim3(16, 1, 64), 256, 0, stream>>>(
        P2I, W4B, c4b, b4g, b4b, nullptr, ENC, nullptr,
        64, 64, 128, 66, 557568L, 1048576L, 64, 256, 4, 1);
    // 7) dc1 256->128 (64->128 up) -> F
    mfma_deconv_k<<<dim3(16, 1, 32), 256, 0, stream>>>(
        ENC, WD1, d1b, F, 64, 64, 256, 128, 2, 1);
    // 8) dc2 128->64 (128->256 up) -> FEAT
    mfma_deconv_k<<<dim3(64, 1, 16), 256, 0, stream>>>(
        F, WD2, d2b, FEAT, 128, 128, 128, 64, 1, 2);
    // 9) head 1x1 + sigmoid -> HDB (padded bf16 nhwc) + INITHM (f32 nchw)
    //    zero HDB halo first (shares R2 with F, now dead)
    zero_halo_k<<<(1052672 + 255)/256, 256, 0, stream>>>(HDB, 256, 256, 64, 16);
    mfma_conv_k<1, 3><<<dim3(256, 1, 16), 256, 51456, stream>>>(
        FEAT, WHB, hb, nullptr, nullptr, nullptr, HDI, INITHM,
        256, 256, 64, 256, 4194304L, 4260096L, 258, 64, 1, 4);
    // 10) soft-argmax
    softargmax_k<<<528, 256, 0, stream>>>(INITHM, CO);
    // 11) bilinear + proj
    joint_bf_k<<<528, 64, 0, stream>>>(FEAT, CO, pw, pb, JF);
    // 12) message + GRU -> refined_bias
    gru_k<<<528, 192, 0, stream>>>(JF, mw, mb, wih, whh, bih, bhh, RB);
    // 13) refine 33->33 @256 (48-cout tile) + bias + sigmoid -> out_hm (f32 nchw)
    mfma_conv_k<2, 3><<<dim3(256, 1, 16), 256, 51456, stream>>>(
        HDI, WRB, rb, nullptr, nullptr, RB, nullptr, out_hm,
        256, 256, 64, 258, 4260096L, 0L, 0, 64, 1, 4);
    // 14) vis pool -> P (16,4096)
    vispool_bf_k<<<256, 256, 0, stream>>>(ENC, P);
    // 15) fc1 + relu
    visfc1_k<<<16, 256, 0, stream>>>(P, v1w, v1b, V1);
    // 16) fc2 + sigmoid
    visfc2_k<<<16, 64, 0, stream>>>(V1, v2w, v2b, out_vis);
}